// Round 6
// baseline (133.807 us; speedup 1.0000x reference)
//
#include <hip/hip_runtime.h>
#include <hip/hip_fp16.h>

#define D 512
#define NTOK 512
#define BINS 64

typedef float v4f __attribute__((ext_vector_type(4)));
typedef int v4i __attribute__((ext_vector_type(4)));
typedef short short8 __attribute__((ext_vector_type(8)));
typedef _Float16 h8 __attribute__((ext_vector_type(8)));
typedef _Float16 h4 __attribute__((ext_vector_type(4)));

// packed f16 tanh-approx gelu, trans-minimized form (2 transcendentals per
// half2). Reflect through a=|x|: q = -(2.3022082+0.1029437*a^2)*a <= 0,
// e = 2^q in (0,1], sigma = 1/(1+e) = 1 + e*n'(e), n' cubic (Chebyshev on
// [0,1], |err| <= 1.2e-3 * e -> worst-case gelu err ~2.8e-4, below f16
// quantum). Sign fold exact: min(x,0) = (x - |x|) * 0.5.
__device__ __forceinline__ __half2 gelu2(__half2 x) {
    __half2 a = __builtin_bit_cast(__half2, __builtin_bit_cast(int, x) & 0x7fff7fff);
    __half2 s = __hmul2(a, a);
    __half2 m = __hfma2(s, __float2half2_rn(-0.1029437f),
                           __float2half2_rn(-2.3022082f));
    __half2 q = __hmul2(a, m);
    __half2 e = h2exp2(q);                     // (0, 1]
    __half2 n = __hfma2(e, __float2half2_rn(0.228584f),  __float2half2_rn(-0.675920f));
    n = __hfma2(e, n, __float2half2_rn(0.946902f));
    n = __hfma2(e, n, __float2half2_rn(-0.998521f));
    __half2 p = __hfma2(e, n, __float2half2_rn(1.0f));   // sigma = 1 + e*n'
    __half2 xneg = __hmul2(__hsub2(x, a), __float2half2_rn(0.5f));  // min(x,0)
    return __hfma2(a, p, xneg);
}

__device__ __forceinline__ __half2 bc_h2(int v) { return __builtin_bit_cast(__half2, v); }
__device__ __forceinline__ int bc_i(__half2 v) { return __builtin_bit_cast(int, v); }

// Merged prep kernel: projection GEMM with pack-on-the-fly operands + W2 pack.
// Replaces k_pack+k_gemm (one fewer launch; no Ap/Wp workspace round-trip).
// MFMA 16x16x32 f16 fragment layouts (verified lane maps):
//   A-frag: lane l holds A[l&15][(l>>4)*8 + j]  (row-major 8 contiguous k)
//   B-frag: lane l holds B[(l>>4)*8 + j][l&15]  (k-major per out-col)
//   D:      col = l&15, row = (l>>4)*4 + reg
// Blocks 0..511: H[512,1024] = x @ [W1a|W1b]; 32 mb x 16 cb, wave w owns
//   nb = cb*4+w. A-frag: 2x v4f from x row (l&15) + cvt. B-frag: 8 strided f32
//   gathers (16 lanes read 16 consecutive cols of one W1 k-row -> 64B segs)
//   + cvt. 16 MFMA, f32 accum, +b1 on hi half, f16 RTE store.
// Blocks 512..527: W2 -> Bp fragment pack (unchanged).
__global__ __launch_bounds__(256) void k_prep(const float* __restrict__ x,
                                              const float* __restrict__ W1,
                                              const float* __restrict__ b1,
                                              const float* __restrict__ W2,
                                              _Float16* __restrict__ hi,
                                              _Float16* __restrict__ hj,
                                              short8* __restrict__ Bp) {
    const int b = blockIdx.x;
    const int t = threadIdx.x;
    if (b >= 512) {          // W2 -> Bp
        const int tid = (b - 512) * 256 + t;     // 0..4095
        const int ll = tid & 63;
        const int nt = (tid >> 6) & 3;
        const int kt = tid >> 8;
        const int colp = nt * 16 + (ll & 15);
        const int krow = kt * 32 + (ll >> 4) * 8;
        short8 v;
#pragma unroll
        for (int u = 0; u < 8; ++u) {
            _Float16 hv = (_Float16)W2[(size_t)(krow + u) * BINS + colp];  // RTE
            v[u] = __builtin_bit_cast(short, hv);
        }
        Bp[tid] = v;
        return;
    }
    const int l = t & 63;
    const int w = t >> 6;
    const int c = l & 15;
    const int q = l >> 4;
    const int mb = b >> 4;                       // 0..31
    const int cb = b & 15;
    const int nb = cb * 4 + w;
    const int ng = nb * 16 + c;                  // combined out col 0..1023

    const float* xa = x + (size_t)(mb * 16 + c) * D + q * 8;
    const float* wsrc = W1 + (size_t)((ng >> 9) * D + q * 8) * D + (ng & 511);

    v4f acc = {0.f, 0.f, 0.f, 0.f};
#pragma unroll 4
    for (int ks = 0; ks < 16; ++ks) {
        v4f a0 = *(const v4f*)(xa + ks * 32);
        v4f a1 = *(const v4f*)(xa + ks * 32 + 4);
        h8 af;
        af[0] = (_Float16)a0.x; af[1] = (_Float16)a0.y;
        af[2] = (_Float16)a0.z; af[3] = (_Float16)a0.w;
        af[4] = (_Float16)a1.x; af[5] = (_Float16)a1.y;
        af[6] = (_Float16)a1.z; af[7] = (_Float16)a1.w;
        h8 bf;
#pragma unroll
        for (int j = 0; j < 8; ++j)
            bf[j] = (_Float16)wsrc[(size_t)(ks * 32 + j) * D];  // RTE
        acc = __builtin_amdgcn_mfma_f32_16x16x32_f16(af, bf, acc, 0, 0, 0);
    }

    const float b1v = (ng < D) ? b1[ng] : 0.0f;
    _Float16* dst = (ng < D ? hi : hj) + (ng & 511);
    const int row0 = mb * 16 + q * 4;
#pragma unroll
    for (int r = 0; r < 4; ++r)
        dst[(size_t)(row0 + r) * D] = (_Float16)(acc[r] + b1v);
}

// Main fused kernel — software-pipeline round. Grid 2048 = 64 i-tiles (8 rows)
// x 32 j-tiles (16 cols); 4 waves/block, wave w owns 2 i-rows (acc[2][4]).
// Full kt-unroll with 2-deep cur/nxt register rotation: iteration kt's ~240
// VALU ops run while kt+1's 7 L2 loads (hjr, 4x bfr, 2x ar) are in flight —
// cross-iteration ILP the non-unrolled loop denied the compiler (r2/r4/r5
// falsified barriers/trans/occupancy; latency exposure is the remaining lever).
// launch_bounds(256,3): ~170-reg cap, est. peak ~140, no spill.
__global__ __launch_bounds__(256, 3) void k_main(const __half* __restrict__ hi,
                                                 const __half* __restrict__ hj,
                                                 const v4i* __restrict__ Bp,
                                                 const float* __restrict__ b2,
                                                 float* __restrict__ out) {
    const int l = threadIdx.x & 63;
    const int w = threadIdx.x >> 6;
    const int c = l & 15;   // MFMA col: A m-index (j-offset) / B,D n-offset
    const int q = l >> 4;   // quad: k-group for A/B, row-group for D
    const int ib = (blockIdx.x >> 5) * 8;
    const int j0 = (blockIdx.x & 31) * 16;

    const __half* hjp = hj + (size_t)(j0 + c) * D + q * 8;
    const __half* hip = hi + (size_t)(ib + w * 2) * D + q * 8;
    const v4i* bp = Bp + l;

    v4f acc[2][4] = {};  // [p(i)][nt]

    v4i hjr[2];
    v4i bfr[2][4];
    v4i ar[2][2];
    hjr[0] = *(const v4i*)hjp;
#pragma unroll
    for (int nt = 0; nt < 4; ++nt) bfr[0][nt] = bp[nt * 64];
#pragma unroll
    for (int p = 0; p < 2; ++p) ar[0][p] = *(const v4i*)(hip + (size_t)p * D);

#pragma unroll
    for (int kt = 0; kt < 16; ++kt) {
        const int cur = kt & 1, nxt = cur ^ 1;
        if (kt < 15) {                           // prefetch kt+1 (7 loads)
            const int ko = (kt + 1) * 32;
            hjr[nxt] = *(const v4i*)(hjp + ko);
#pragma unroll
            for (int nt = 0; nt < 4; ++nt)
                bfr[nxt][nt] = bp[((kt + 1) * 4 + nt) * 64];
#pragma unroll
            for (int p = 0; p < 2; ++p)
                ar[nxt][p] = *(const v4i*)(hip + (size_t)p * D + ko);
        }
        __half2 j0h = bc_h2(hjr[cur].x), j1h = bc_h2(hjr[cur].y);
        __half2 j2h = bc_h2(hjr[cur].z), j3h = bc_h2(hjr[cur].w);
#pragma unroll
        for (int p = 0; p < 2; ++p) {
            v4i arr = ar[cur][p];
            __half2 g0 = gelu2(__hadd2(bc_h2(arr.x), j0h));
            __half2 g1 = gelu2(__hadd2(bc_h2(arr.y), j1h));
            __half2 g2 = gelu2(__hadd2(bc_h2(arr.z), j2h));
            __half2 g3 = gelu2(__hadd2(bc_h2(arr.w), j3h));
            v4i ai = {bc_i(g0), bc_i(g1), bc_i(g2), bc_i(g3)};
            h8 af = __builtin_bit_cast(h8, ai);
#pragma unroll
            for (int nt = 0; nt < 4; ++nt)
                acc[p][nt] = __builtin_amdgcn_mfma_f32_16x16x32_f16(
                    af, __builtin_bit_cast(h8, bfr[cur][nt]), acc[p][nt], 0, 0, 0);
        }
    }

    const int i0 = ib + w * 2;
#pragma unroll
    for (int p = 0; p < 2; ++p) {
        const size_t rowbase = ((size_t)(i0 + p) * NTOK + j0 + q * 4) * BINS;
#pragma unroll
        for (int nt = 0; nt < 4; ++nt) {
            const float bb = b2[nt * 16 + c];
            float* op = out + rowbase + nt * 16 + c;
#pragma unroll
            for (int rr = 0; rr < 4; ++rr)
                op[(size_t)rr * BINS] = acc[p][nt][rr] + bb;
        }
    }
}

extern "C" void kernel_launch(void* const* d_in, const int* in_sizes, int n_in,
                              void* d_out, int out_size, void* d_ws, size_t ws_size,
                              hipStream_t stream) {
    const float* x  = (const float*)d_in[0];
    const float* W1 = (const float*)d_in[1];
    const float* b1 = (const float*)d_in[2];
    const float* W2 = (const float*)d_in[3];
    const float* b2 = (const float*)d_in[4];
    float* out = (float*)d_out;

    char* ws = (char*)d_ws;
    __half* hi = (__half*)ws;                          // 512 KB
    __half* hj = (__half*)(ws + (512u << 10));         // 512 KB
    short8* Bp = (short8*)(ws + (1u << 20));           // 64 KB

    k_prep<<<528, 256, 0, stream>>>(x, W1, b1, W2, (_Float16*)hi, (_Float16*)hj, Bp);
    k_main<<<2048, 256, 0, stream>>>(hi, hj, (const v4i*)Bp, b2, out);
}

// Round 7
// 125.755 us; speedup vs baseline: 1.0640x; 1.0640x over previous
//
#include <hip/hip_runtime.h>
#include <hip/hip_fp16.h>

#define D 512
#define NTOK 512
#define BINS 64

typedef float v4f __attribute__((ext_vector_type(4)));
typedef int v4i __attribute__((ext_vector_type(4)));
typedef short short8 __attribute__((ext_vector_type(8)));
typedef _Float16 h8 __attribute__((ext_vector_type(8)));

// packed f16 gelu, trans-minimized (2 transcendentals per half2).
// a=|x|; q=-(2.3022082+0.1029437a^2)a <= 0; e=2^q in (0,1];
// sigma = 1/(1+e) ~= 1 + e*n'(e), n' cubic Chebyshev on [0,1] (|err|<=1.2e-3*e
// -> gelu abs err ~2.8e-4, below f16 quantum). min(x,0) = (x-|x|)*0.5 exact.
__device__ __forceinline__ __half2 gelu2(__half2 x) {
    __half2 a = __builtin_bit_cast(__half2, __builtin_bit_cast(int, x) & 0x7fff7fff);
    __half2 s = __hmul2(a, a);
    __half2 m = __hfma2(s, __float2half2_rn(-0.1029437f),
                           __float2half2_rn(-2.3022082f));
    __half2 q = __hmul2(a, m);
    __half2 e = h2exp2(q);                     // (0, 1]
    __half2 n = __hfma2(e, __float2half2_rn(0.228584f),  __float2half2_rn(-0.675920f));
    n = __hfma2(e, n, __float2half2_rn(0.946902f));
    n = __hfma2(e, n, __float2half2_rn(-0.998521f));
    __half2 p = __hfma2(e, n, __float2half2_rn(1.0f));   // sigma = 1 + e*n'
    __half2 xneg = __hmul2(__hsub2(x, a), __float2half2_rn(0.5f));  // min(x,0)
    return __hfma2(a, p, xneg);
}

__device__ __forceinline__ __half2 bc_h2(int v) { return __builtin_bit_cast(__half2, v); }
__device__ __forceinline__ int bc_i(__half2 v) { return __builtin_bit_cast(int, v); }

__device__ __forceinline__ v4i pack8(v4f a, v4f b) {
    h8 o;
    o[0] = (_Float16)a.x; o[1] = (_Float16)a.y; o[2] = (_Float16)a.z; o[3] = (_Float16)a.w;
    o[4] = (_Float16)b.x; o[5] = (_Float16)b.y; o[6] = (_Float16)b.z; o[7] = (_Float16)b.w;
    return __builtin_bit_cast(v4i, o);
}

// DMA 16B global -> LDS (wave-uniform LDS base + lane*16 implicit scatter).
__device__ __forceinline__ void g2lds16(const void* g, void* l) {
    __builtin_amdgcn_global_load_lds(
        (const __attribute__((address_space(1))) void*)g,
        (__attribute__((address_space(3))) void*)l, 16, 0, 0);
}

#define WAITVM_(N) asm volatile("s_waitcnt vmcnt(" #N ")" ::: "memory")
#define WAITVM(N) WAITVM_(N)

// ---- k_pack / k_gemm: restored r2 split (merged k_prep regressed ~6us:
// 512 proj blocks re-gathered W1 32x with strided loads; pack-once is cheaper).
__global__ __launch_bounds__(256) void k_pack(const float* __restrict__ x,
                                              const float* __restrict__ W1,
                                              const float* __restrict__ W2,
                                              v4i* __restrict__ Ap,
                                              v4i* __restrict__ Wp,
                                              short8* __restrict__ Bp) {
    const int b = blockIdx.x;
    const int t = threadIdx.x;
    if (b < 32) {            // x fragments: 32 rb x 16 ks x 64 lanes
        const int rb = b;
#pragma unroll
        for (int u = 0; u < 4; ++u) {
            const int e = t + 256 * u;           // 0..1023
            const int l = e & 63, ks = e >> 6;
            const float* src = x + (size_t)(rb * 16 + (l & 15)) * D + ks * 32 + (l >> 4) * 8;
            v4f a = *(const v4f*)src;
            v4f c = *(const v4f*)(src + 4);
            Ap[(size_t)(rb * 16 + ks) * 64 + l] = pack8(a, c);
        }
    } else if (b < 288) {    // W1 fragments: one slot per thread
        const int slot = (b - 32) * 256 + t;     // 0..65535
        const int l = slot & 63;
        const int ks = (slot >> 6) & 15;
        const int nb = slot >> 10;               // 0..63
        const int ng = nb * 16 + (l & 15);       // combined out col 0..1023
        const float* src = W1 + (size_t)((ng >> 9) * D + ks * 32 + (l >> 4) * 8) * D
                              + (ng & 511);
        h8 o;
#pragma unroll
        for (int j = 0; j < 8; ++j) o[j] = (_Float16)src[(size_t)j * D];  // RTE
        Wp[(size_t)(nb * 16 + ks) * 64 + l] = __builtin_bit_cast(v4i, o);
    } else {                 // W2 -> Bp
        const int tid = (b - 288) * 256 + t;     // 0..4095
        const int ll = tid & 63;
        const int nt = (tid >> 6) & 3;
        const int kt = tid >> 8;
        const int colp = nt * 16 + (ll & 15);
        const int krow = kt * 32 + (ll >> 4) * 8;
        short8 v;
#pragma unroll
        for (int u = 0; u < 8; ++u) {
            _Float16 hv = (_Float16)W2[(size_t)(krow + u) * BINS + colp];  // RTE
            v[u] = __builtin_bit_cast(short, hv);
        }
        Bp[tid] = v;
    }
}

__global__ __launch_bounds__(256) void k_gemm(const v4i* __restrict__ Ap,
                                              const v4i* __restrict__ Wp,
                                              const float* __restrict__ b1,
                                              _Float16* __restrict__ hi,
                                              _Float16* __restrict__ hj) {
    const int l = threadIdx.x & 63;
    const int w = threadIdx.x >> 6;
    const int c = l & 15;
    const int q = l >> 4;
    const int mb = blockIdx.x >> 4;              // 0..31
    const int cb = blockIdx.x & 15;
    const int nb = cb * 4 + w;

    const v4i* ap = Ap + (size_t)mb * 16 * 64 + l;
    const v4i* wp = Wp + (size_t)nb * 16 * 64 + l;

    v4f acc = {0.f, 0.f, 0.f, 0.f};
#pragma unroll 4
    for (int ks = 0; ks < 16; ++ks) {
        v4i a0 = ap[ks * 64];
        v4i bb = wp[ks * 64];
        acc = __builtin_amdgcn_mfma_f32_16x16x32_f16(__builtin_bit_cast(h8, a0),
                                                     __builtin_bit_cast(h8, bb), acc, 0, 0, 0);
    }

    const int ng = nb * 16 + c;
    const float b1v = (ng < D) ? b1[ng] : 0.0f;
    _Float16* dst = (ng < D ? hi : hj) + (ng & 511);
    const int row0 = mb * 16 + q * 4;
#pragma unroll
    for (int r = 0; r < 4; ++r)
        dst[(size_t)(row0 + r) * D] = (_Float16)(acc[r] + b1v);
}

// ---- k_main: counted-vmcnt DMA pipeline (T3+T4 pattern).
// Grid 1024 = 64 i-tiles(16) x ... wait: 32x32 tiles: ib=(bid>>5)*16, j0=(bid&31)*16.
// 4 waves, wave w owns 4 i-rows (acc[4][4]).
// Per kt (32 d): 6KB LDS tile {Bp 4KB | hj 1KB | hi 1KB}, staged via
// global_load_lds into a 5-deep ring, stage-ahead 3, ONE raw s_barrier per kt,
// per-wave counted vmcnt (never 0 until tail). DMA uses no VGPRs -> compiler
// cannot defeat the pipeline (r6's register prefetch was sunk at VGPR=52).
// Ring safety: buf written at iter kt was last read by compute(kt-2), which all
// waves completed before barrier(kt-1), already passed (NBUF=5 = ahead+2).
#define NBUF 5
#define BUFSZ 6144
__global__ __launch_bounds__(256, 3) void k_main(const __half* __restrict__ hi,
                                                 const __half* __restrict__ hj,
                                                 const float* __restrict__ b2,
                                                 const char* __restrict__ BpB,
                                                 float* __restrict__ out) {
    const int l = threadIdx.x & 63;
    const int w = threadIdx.x >> 6;
    const int c = l & 15;   // MFMA col: A m-index (j-offset) / B,D n-offset
    const int q = l >> 4;   // quad: k-group for A/B, row-group for D
    const int ib = (blockIdx.x >> 5) * 16;
    const int j0 = (blockIdx.x & 31) * 16;

    __shared__ __align__(16) char lds[NBUF * BUFSZ];   // 30720 B

    const char* hjB = (const char*)hj;
    const char* hiB = (const char*)hi;

    // stage tile kt into ring buffer bi: wave w -> Bp slots w*64.., 16B/lane.
    // wave 0 also stages hj (slot l <-> row j0+(l&15), 16B unit (l>>4)),
    // wave 1 also stages hi (slot l <-> row ib+(l>>2), 16B unit (l&3)).
#define STAGE(kt_, bi_)                                                          \
    {                                                                            \
        char* buf_ = lds + (bi_) * BUFSZ;                                        \
        g2lds16(BpB + (size_t)(kt_) * 4096 + (w * 64 + l) * 16, buf_ + w * 1024);\
        if (w == 0)                                                              \
            g2lds16(hjB + (size_t)(j0 + (l & 15)) * 1024 + (kt_) * 64 + (l >> 4) * 16, \
                    buf_ + 4096);                                                \
        if (w == 1)                                                              \
            g2lds16(hiB + (size_t)(ib + (l >> 2)) * 1024 + (kt_) * 64 + (l & 3) * 16,  \
                    buf_ + 5120);                                                \
    }

    v4f acc[4][4] = {};  // [p(i)][nt]

    STAGE(0, 0) STAGE(1, 1) STAGE(2, 2)

#pragma unroll
    for (int kt = 0; kt < 16; ++kt) {
        if (kt + 3 < 16) STAGE(kt + 3, (kt + 3) % NBUF)
        const int rem = (kt <= 12) ? 3 : 15 - kt;   // stages still in flight after kt's
        if (w < 2) {
            if (rem == 3) WAITVM(6); else if (rem == 2) WAITVM(4);
            else if (rem == 1) WAITVM(2); else WAITVM(0);
        } else {
            if (rem == 3) WAITVM(3); else if (rem == 2) WAITVM(2);
            else if (rem == 1) WAITVM(1); else WAITVM(0);
        }
        __builtin_amdgcn_s_barrier();

        const char* buf = lds + (kt % NBUF) * BUFSZ;
        const v4i* bsec = (const v4i*)buf;               // Bp: slot nt*64 + l
        v4i bfr[4];
#pragma unroll
        for (int nt = 0; nt < 4; ++nt) bfr[nt] = bsec[nt * 64 + l];
        v4i hjraw = ((const v4i*)(buf + 4096))[l];
        __half2 j0h = bc_h2(hjraw.x), j1h = bc_h2(hjraw.y);
        __half2 j2h = bc_h2(hjraw.z), j3h = bc_h2(hjraw.w);
#pragma unroll
        for (int p = 0; p < 4; ++p) {
            v4i ar = *(const v4i*)(buf + 5120 + ((w * 4 + p) * 4 + q) * 16);
            __half2 g0 = gelu2(__hadd2(bc_h2(ar.x), j0h));
            __half2 g1 = gelu2(__hadd2(bc_h2(ar.y), j1h));
            __half2 g2 = gelu2(__hadd2(bc_h2(ar.z), j2h));
            __half2 g3 = gelu2(__hadd2(bc_h2(ar.w), j3h));
            v4i ai = {bc_i(g0), bc_i(g1), bc_i(g2), bc_i(g3)};
            h8 af = __builtin_bit_cast(h8, ai);
#pragma unroll
            for (int nt = 0; nt < 4; ++nt)
                acc[p][nt] = __builtin_amdgcn_mfma_f32_16x16x32_f16(
                    af, __builtin_bit_cast(h8, bfr[nt]), acc[p][nt], 0, 0, 0);
        }
    }
#undef STAGE

    const int i0 = ib + w * 4;
#pragma unroll
    for (int p = 0; p < 4; ++p) {
        const size_t rowbase = ((size_t)(i0 + p) * NTOK + j0 + q * 4) * BINS;
#pragma unroll
        for (int nt = 0; nt < 4; ++nt) {
            const float bb = b2[nt * 16 + c];
            float* op = out + rowbase + nt * 16 + c;
#pragma unroll
            for (int rr = 0; rr < 4; ++rr)
                op[(size_t)rr * BINS] = acc[p][nt][rr] + bb;
        }
    }
}

extern "C" void kernel_launch(void* const* d_in, const int* in_sizes, int n_in,
                              void* d_out, int out_size, void* d_ws, size_t ws_size,
                              hipStream_t stream) {
    const float* x  = (const float*)d_in[0];
    const float* W1 = (const float*)d_in[1];
    const float* b1 = (const float*)d_in[2];
    const float* W2 = (const float*)d_in[3];
    const float* b2 = (const float*)d_in[4];
    float* out = (float*)d_out;

    char* ws = (char*)d_ws;
    __half* hi = (__half*)ws;                          // 512 KB
    __half* hj = (__half*)(ws + (512u << 10));         // 512 KB
    short8* Bp = (short8*)(ws + (1u << 20));           // 64 KB
    v4i*    Ap = (v4i*)(ws + (1u << 20) + (64u << 10));            // 512 KB
    v4i*    Wp = (v4i*)(ws + (1u << 20) + (64u << 10) + (512u << 10));  // 1 MB

    k_pack<<<304, 256, 0, stream>>>(x, W1, W2, Ap, Wp, Bp);
    k_gemm<<<512, 256, 0, stream>>>(Ap, Wp, b1, (_Float16*)hi, (_Float16*)hj);
    k_main<<<1024, 256, 0, stream>>>(hi, hj, b2, (const char*)Bp, out);
}

// Round 8
// 122.800 us; speedup vs baseline: 1.0896x; 1.0241x over previous
//
#include <hip/hip_runtime.h>
#include <hip/hip_fp16.h>

#define D 512
#define NTOK 512
#define BINS 64

typedef float v4f __attribute__((ext_vector_type(4)));
typedef int v4i __attribute__((ext_vector_type(4)));
typedef short short8 __attribute__((ext_vector_type(8)));
typedef _Float16 h8 __attribute__((ext_vector_type(8)));

// packed f16 tanh-approx gelu: x * sigmoid(1.5957691x + 0.0713548x^3), exp2
// form, 9 insts (r2-measured faster than the 12-inst trans-min variant).
// f16 saturation gives correct limits: e=inf -> rcp=0 -> gelu=0 (x<<0);
// e->0 -> rcp(1)=1 -> gelu=x (x>>0).
__device__ __forceinline__ __half2 gelu2(__half2 x) {
    __half2 s = __hmul2(x, x);
    __half2 q = __hmul2(x, __hfma2(s, __float2half2_rn(-0.1029437f),
                                      __float2half2_rn(-2.3022082f)));
    __half2 e = h2exp2(q);
    __half2 r = h2rcp(__hadd2(e, __float2half2_rn(1.0f)));
    return __hmul2(x, r);
}

__device__ __forceinline__ __half2 bc_h2(int v) { return __builtin_bit_cast(__half2, v); }
__device__ __forceinline__ int bc_i(__half2 v) { return __builtin_bit_cast(int, v); }

__device__ __forceinline__ v4i pack8(v4f a, v4f b) {
    h8 o;
    o[0] = (_Float16)a.x; o[1] = (_Float16)a.y; o[2] = (_Float16)a.z; o[3] = (_Float16)a.w;
    o[4] = (_Float16)b.x; o[5] = (_Float16)b.y; o[6] = (_Float16)b.z; o[7] = (_Float16)b.w;
    return __builtin_bit_cast(v4i, o);
}

// DMA 16B global -> LDS (wave-uniform LDS base + lane*16 implicit scatter).
__device__ __forceinline__ void g2lds16(const void* g, void* l) {
    __builtin_amdgcn_global_load_lds(
        (const __attribute__((address_space(1))) void*)g,
        (__attribute__((address_space(3))) void*)l, 16, 0, 0);
}

#define WAITVM_(N) asm volatile("s_waitcnt vmcnt(" #N ")" ::: "memory")
#define WAITVM(N) WAITVM_(N)

// ---- k_pack: operand packing (unchanged from r7).
__global__ __launch_bounds__(256) void k_pack(const float* __restrict__ x,
                                              const float* __restrict__ W1,
                                              const float* __restrict__ W2,
                                              v4i* __restrict__ Ap,
                                              v4i* __restrict__ Wp,
                                              short8* __restrict__ Bp) {
    const int b = blockIdx.x;
    const int t = threadIdx.x;
    if (b < 32) {            // x fragments: 32 rb x 16 ks x 64 lanes
        const int rb = b;
#pragma unroll
        for (int u = 0; u < 4; ++u) {
            const int e = t + 256 * u;           // 0..1023
            const int l = e & 63, ks = e >> 6;
            const float* src = x + (size_t)(rb * 16 + (l & 15)) * D + ks * 32 + (l >> 4) * 8;
            v4f a = *(const v4f*)src;
            v4f c = *(const v4f*)(src + 4);
            Ap[(size_t)(rb * 16 + ks) * 64 + l] = pack8(a, c);
        }
    } else if (b < 288) {    // W1 fragments: one slot per thread
        const int slot = (b - 32) * 256 + t;     // 0..65535
        const int l = slot & 63;
        const int ks = (slot >> 6) & 15;
        const int nb = slot >> 10;               // 0..63
        const int ng = nb * 16 + (l & 15);       // combined out col 0..1023
        const float* src = W1 + (size_t)((ng >> 9) * D + ks * 32 + (l >> 4) * 8) * D
                              + (ng & 511);
        h8 o;
#pragma unroll
        for (int j = 0; j < 8; ++j) o[j] = (_Float16)src[(size_t)j * D];  // RTE
        Wp[(size_t)(nb * 16 + ks) * 64 + l] = __builtin_bit_cast(v4i, o);
    } else {                 // W2 -> Bp
        const int tid = (b - 288) * 256 + t;     // 0..4095
        const int ll = tid & 63;
        const int nt = (tid >> 6) & 3;
        const int kt = tid >> 8;
        const int colp = nt * 16 + (ll & 15);
        const int krow = kt * 32 + (ll >> 4) * 8;
        short8 v;
#pragma unroll
        for (int u = 0; u < 8; ++u) {
            _Float16 hv = (_Float16)W2[(size_t)(krow + u) * BINS + colp];  // RTE
            v[u] = __builtin_bit_cast(short, hv);
        }
        Bp[tid] = v;
    }
}

// ---- k_gemm: projection GEMM (r7 structure; load loop fully unrolled for MLP).
__global__ __launch_bounds__(256) void k_gemm(const v4i* __restrict__ Ap,
                                              const v4i* __restrict__ Wp,
                                              const float* __restrict__ b1,
                                              _Float16* __restrict__ hi,
                                              _Float16* __restrict__ hj) {
    const int l = threadIdx.x & 63;
    const int w = threadIdx.x >> 6;
    const int c = l & 15;
    const int q = l >> 4;
    const int mb = blockIdx.x >> 4;              // 0..31
    const int cb = blockIdx.x & 15;
    const int nb = cb * 4 + w;

    const v4i* ap = Ap + (size_t)mb * 16 * 64 + l;
    const v4i* wp = Wp + (size_t)nb * 16 * 64 + l;

    v4f acc = {0.f, 0.f, 0.f, 0.f};
#pragma unroll
    for (int ks = 0; ks < 16; ++ks) {
        v4i a0 = ap[ks * 64];
        v4i bb = wp[ks * 64];
        acc = __builtin_amdgcn_mfma_f32_16x16x32_f16(__builtin_bit_cast(h8, a0),
                                                     __builtin_bit_cast(h8, bb), acc, 0, 0, 0);
    }

    const int ng = nb * 16 + c;
    const float b1v = (ng < D) ? b1[ng] : 0.0f;
    _Float16* dst = (ng < D ? hi : hj) + (ng & 511);
    const int row0 = mb * 16 + q * 4;
#pragma unroll
    for (int r = 0; r < 4; ++r)
        dst[(size_t)(row0 + r) * D] = (_Float16)(acc[r] + b1v);
}

// ---- k_main: counted-vmcnt DMA pipeline, occupancy round.
// NBUF 5->4 (24KB LDS), stage-ahead 3->2, launch_bounds(256,4): 4 blocks/CU
// (96KB LDS, ~124 unified regs <= 128). Ring safety: buf written at iter kt
// (for tile kt+2, index (kt+2)%4) was last read by compute(kt-2) (same index),
// which all waves finished before barrier(kt-1), which the staging wave passed.
// Per-wave counted vmcnt never drains to 0 until the tail.
#define NBUF 4
#define BUFSZ 6144
__global__ __launch_bounds__(256, 4) void k_main(const __half* __restrict__ hi,
                                                 const __half* __restrict__ hj,
                                                 const float* __restrict__ b2,
                                                 const char* __restrict__ BpB,
                                                 float* __restrict__ out) {
    const int l = threadIdx.x & 63;
    const int w = threadIdx.x >> 6;
    const int c = l & 15;   // MFMA col: A m-index (j-offset) / B,D n-offset
    const int q = l >> 4;   // quad: k-group for A/B, row-group for D
    const int ib = (blockIdx.x >> 5) * 16;
    const int j0 = (blockIdx.x & 31) * 16;

    __shared__ __align__(16) char lds[NBUF * BUFSZ];   // 24576 B

    const char* hjB = (const char*)hj;
    const char* hiB = (const char*)hi;

    // stage tile kt into ring buffer bi: wave w -> Bp slots w*64.., 16B/lane.
    // wave 0 also stages hj (slot l <-> row j0+(l&15), 16B unit (l>>4)),
    // wave 1 also stages hi (slot l <-> row ib+(l>>2), 16B unit (l&3)).
#define STAGE(kt_, bi_)                                                          \
    {                                                                            \
        char* buf_ = lds + (bi_) * BUFSZ;                                        \
        g2lds16(BpB + (size_t)(kt_) * 4096 + (w * 64 + l) * 16, buf_ + w * 1024);\
        if (w == 0)                                                              \
            g2lds16(hjB + (size_t)(j0 + (l & 15)) * 1024 + (kt_) * 64 + (l >> 4) * 16, \
                    buf_ + 4096);                                                \
        if (w == 1)                                                              \
            g2lds16(hiB + (size_t)(ib + (l >> 2)) * 1024 + (kt_) * 64 + (l & 3) * 16,  \
                    buf_ + 5120);                                                \
    }

    v4f acc[4][4] = {};  // [p(i)][nt]

    STAGE(0, 0) STAGE(1, 1)

#pragma unroll
    for (int kt = 0; kt < 16; ++kt) {
        if (kt + 2 < 16) STAGE(kt + 2, (kt + 2) % NBUF)
        const int rem = (kt <= 13) ? 2 : 15 - kt;   // stages still in flight after kt's
        if (w < 2) {
            if (rem == 2) WAITVM(4); else if (rem == 1) WAITVM(2); else WAITVM(0);
        } else {
            if (rem == 2) WAITVM(2); else if (rem == 1) WAITVM(1); else WAITVM(0);
        }
        __builtin_amdgcn_s_barrier();

        const char* buf = lds + (kt % NBUF) * BUFSZ;
        const v4i* bsec = (const v4i*)buf;               // Bp: slot nt*64 + l
        v4i bfr[4];
#pragma unroll
        for (int nt = 0; nt < 4; ++nt) bfr[nt] = bsec[nt * 64 + l];
        v4i hjraw = ((const v4i*)(buf + 4096))[l];
        __half2 j0h = bc_h2(hjraw.x), j1h = bc_h2(hjraw.y);
        __half2 j2h = bc_h2(hjraw.z), j3h = bc_h2(hjraw.w);
#pragma unroll
        for (int p = 0; p < 4; ++p) {
            v4i ar = *(const v4i*)(buf + 5120 + ((w * 4 + p) * 4 + q) * 16);
            __half2 g0 = gelu2(__hadd2(bc_h2(ar.x), j0h));
            __half2 g1 = gelu2(__hadd2(bc_h2(ar.y), j1h));
            __half2 g2 = gelu2(__hadd2(bc_h2(ar.z), j2h));
            __half2 g3 = gelu2(__hadd2(bc_h2(ar.w), j3h));
            v4i ai = {bc_i(g0), bc_i(g1), bc_i(g2), bc_i(g3)};
            h8 af = __builtin_bit_cast(h8, ai);
#pragma unroll
            for (int nt = 0; nt < 4; ++nt)
                acc[p][nt] = __builtin_amdgcn_mfma_f32_16x16x32_f16(
                    af, __builtin_bit_cast(h8, bfr[nt]), acc[p][nt], 0, 0, 0);
        }
    }
#undef STAGE

    const int i0 = ib + w * 4;
#pragma unroll
    for (int p = 0; p < 4; ++p) {
        const size_t rowbase = ((size_t)(i0 + p) * NTOK + j0 + q * 4) * BINS;
#pragma unroll
        for (int nt = 0; nt < 4; ++nt) {
            const float bb = b2[nt * 16 + c];
            float* op = out + rowbase + nt * 16 + c;
#pragma unroll
            for (int rr = 0; rr < 4; ++rr)
                op[(size_t)rr * BINS] = acc[p][nt][rr] + bb;
        }
    }
}

extern "C" void kernel_launch(void* const* d_in, const int* in_sizes, int n_in,
                              void* d_out, int out_size, void* d_ws, size_t ws_size,
                              hipStream_t stream) {
    const float* x  = (const float*)d_in[0];
    const float* W1 = (const float*)d_in[1];
    const float* b1 = (const float*)d_in[2];
    const float* W2 = (const float*)d_in[3];
    const float* b2 = (const float*)d_in[4];
    float* out = (float*)d_out;

    char* ws = (char*)d_ws;
    __half* hi = (__half*)ws;                          // 512 KB
    __half* hj = (__half*)(ws + (512u << 10));         // 512 KB
    short8* Bp = (short8*)(ws + (1u << 20));           // 64 KB
    v4i*    Ap = (v4i*)(ws + (1u << 20) + (64u << 10));            // 512 KB
    v4i*    Wp = (v4i*)(ws + (1u << 20) + (64u << 10) + (512u << 10));  // 1 MB

    k_pack<<<304, 256, 0, stream>>>(x, W1, W2, Ap, Wp, Bp);
    k_gemm<<<512, 256, 0, stream>>>(Ap, Wp, b1, (_Float16*)hi, (_Float16*)hj);
    k_main<<<1024, 256, 0, stream>>>(hi, hj, b2, (const char*)Bp, out);
}